// Round 5
// baseline (477.177 us; speedup 1.0000x reference)
//
#include <hip/hip_runtime.h>

#define BB 8
#define CC_ALL 128
#define HH 160
#define WW 160
#define PAD 4
#define RANGE 9
#define ND 80
#define NG 3                  // di groups (rows 0-2, 3-5, 6-8)
#define DR 3                  // di rows per group -> one per thread
#define TH 8                  // tile height (full width tile: 160 x 8)
#define NTX 40                // lanes per image row
#define PXT 4                 // px per thread along w (aligned float4)
#define NTHREADS 960          // tx(40) * r(3) * ty(8) = 15 waves
#define CCHUNK 4              // halved: double-buffer fits same 53.8 KB LDS
#define NBUF 2
#define NROWS (TH + DR - 1)   // 10 f2 rows cover this group's 3 di offsets
#define ROWF (WW + 2 * PAD)   // 168 floats per LDS row (4 pad each side)
#define BUFF (CCHUNK * NROWS * ROWF)         // floats per buffer = 6720
#define PLANE (HH * WW)       // 25600
#define NQUADS (CCHUNK * NROWS * (WW / 4))   // 1600 float4 per chunk
#define NSLOT 2               // ceil(1600/960): tid<640 stages 2, else 1
#define NACC (RANGE * PXT)    // 36 accumulators per thread

// Second launch_bounds arg MUST stay 1: any min-waves hint makes LLVM cap
// VGPRs and spill acc to scratch (rounds 1-3: 0.8-2.1 GB scratch traffic).
// VGPR budget: must stay <=64 for 2 blocks/CU (8 waves/SIMD).
__global__ __launch_bounds__(NTHREADS, 1)
void cost_volume_kernel(const float* __restrict__ f1,
                        const float* __restrict__ f2,
                        float* __restrict__ out) {
    __shared__ __align__(16) float s2[NBUF][CCHUNK][NROWS][ROWF];   // 53.8 KB

    const int tile_y = blockIdx.x;              // 0..19
    const int bz     = blockIdx.y;              // 0..23
    const int b = bz / NG;
    const int g = bz - b * NG;                  // di group
    const int h0 = tile_y * TH;
    const int tid = threadIdx.x;
    // lane order tx -> r -> ty: duplicate f1 addresses (same tx,ty; diff r)
    // land in the same wave and coalesce to one fetch.
    const int tx = tid % NTX;                   // 0..39
    const int r  = (tid / NTX) % DR;            // 0..2  (this thread's di row)
    const int ty = tid / (NTX * DR);            // 0..7
    const int w = tx * PXT;                     // multiple of 4
    const int h = h0 + ty;
    const int row_start = h0 + DR * g - PAD;    // image row of LDS row 0

    // ---- zero LDS once: pad columns + OOB rows stay zero forever ----
    {
        float* p = &s2[0][0][0][0];
        for (int i = tid; i < NBUF * BUFF; i += NTHREADS) p[i] = 0.f;
    }

    // ---- precompute staging slots (channel- and buffer-invariant) ----
    // slot s -> (cc, row, quad): covers f2[c0+cc][row_start+row][quad*4 .. +3]
    int glb_off[NSLOT];
    int lds_off[NSLOT];
    unsigned vmask = 0;
    {
#pragma unroll
        for (int k = 0; k < NSLOT; k++) {
            const int s = tid + k * NTHREADS;
            const int quad = s % (WW / 4);
            const int t = s / (WW / 4);
            const int row = t % NROWS;
            const int cc = t / NROWS;
            const int gh = row_start + row;
            glb_off[k] = cc * PLANE + gh * WW + quad * 4;
            lds_off[k] = (cc * NROWS + row) * ROWF + PAD + quad * 4;
            if (s < NQUADS && (unsigned)gh < HH) vmask |= (1u << k);
        }
    }

    float acc[NACC];
#pragma unroll
    for (int i = 0; i < NACC; i++) acc[i] = 0.f;

    const float* f1p = f1 + (size_t)b * CC_ALL * PLANE + (size_t)h * WW + w;
    const float* f2b = f2 + (size_t)b * CC_ALL * PLANE;
    float* s2f = &s2[0][0][0][0];

    // ---- prologue: chunk 0 -> regs, commit to buf0, chunk 1 -> regs ----
    float4 rbuf[NSLOT];
#pragma unroll
    for (int k = 0; k < NSLOT; k++)
        if (vmask & (1u << k)) rbuf[k] = *(const float4*)(f2b + glb_off[k]);
    __syncthreads();   // zero-init visible before staging writes
#pragma unroll
    for (int k = 0; k < NSLOT; k++)
        if (vmask & (1u << k)) *(float4*)(s2f + lds_off[k]) = rbuf[k];
#pragma unroll
    for (int k = 0; k < NSLOT; k++)
        if (vmask & (1u << k))
            rbuf[k] = *(const float4*)(f2b + (size_t)CCHUNK * PLANE + glb_off[k]);

    // ---- main loop: ONE barrier per chunk ----
    // iter it: barrier (chunk it writes visible; chunk it-1 readers done)
    //          -> ds_write chunk it+1 to other buf -> issue loads chunk it+2
    //          -> compute chunk it
    for (int it = 0; it < CC_ALL / CCHUNK; ++it) {
        const int c0 = it * CCHUNK;
        __syncthreads();

        const int nbuf_base = ((it + 1) & 1) * BUFF;
        if (c0 + CCHUNK < CC_ALL) {
#pragma unroll
            for (int k = 0; k < NSLOT; k++)
                if (vmask & (1u << k))
                    *(float4*)(s2f + nbuf_base + lds_off[k]) = rbuf[k];
        }
        if (c0 + 2 * CCHUNK < CC_ALL) {
#pragma unroll
            for (int k = 0; k < NSLOT; k++)
                if (vmask & (1u << k))
                    rbuf[k] = *(const float4*)(f2b + (size_t)(c0 + 2 * CCHUNK) * PLANE + glb_off[k]);
        }

        // ---- compute chunk it from buf[it&1] ----
        const float* bufp = s2f + (it & 1) * BUFF;
#pragma unroll
        for (int cc = 0; cc < CCHUNK; cc++) {
            const float4 a = *(const float4*)(f1p + (size_t)(c0 + cc) * PLANE);
            const float av[PXT] = {a.x, a.y, a.z, a.w};
            // LDS cols 4tx .. 4tx+11  <->  image w-4 .. w+7 : 3 aligned b128
            const float* rp = bufp + (cc * NROWS + ty + r) * ROWF + w;
            float win[12];
            *(float4*)&win[0] = *(const float4*)(rp);
            *(float4*)&win[4] = *(const float4*)(rp + 4);
            *(float4*)&win[8] = *(const float4*)(rp + 8);
#pragma unroll
            for (int dj = 0; dj < RANGE; dj++) {
#pragma unroll
                for (int p = 0; p < PXT; p++) {
                    acc[dj * PXT + p] += av[p] * win[dj + p];
                }
            }
        }
    }

    // ---- epilogue: mean and store (skip center lin==40) ----
    float* ob = out + (size_t)b * ND * PLANE + (size_t)h * WW + w;
#pragma unroll
    for (int dj = 0; dj < RANGE; dj++) {
        const int lin = (DR * g + r) * RANGE + dj;
        if (lin == 40) continue;                // center displacement excluded
        const int d = lin - (lin > 40 ? 1 : 0);
        float4 o;
        o.x = acc[dj * PXT + 0] * (1.f / 128.f);
        o.y = acc[dj * PXT + 1] * (1.f / 128.f);
        o.z = acc[dj * PXT + 2] * (1.f / 128.f);
        o.w = acc[dj * PXT + 3] * (1.f / 128.f);
        *(float4*)(ob + (size_t)d * PLANE) = o;
    }
}

extern "C" void kernel_launch(void* const* d_in, const int* in_sizes, int n_in,
                              void* d_out, int out_size, void* d_ws, size_t ws_size,
                              hipStream_t stream) {
    const float* feat1 = (const float*)d_in[0];
    const float* feat2 = (const float*)d_in[1];
    float* out = (float*)d_out;

    dim3 grid(HH / TH, BB * NG);   // 20 x 24 = 480 blocks of 15 waves
    dim3 block(NTHREADS);
    cost_volume_kernel<<<grid, block, 0, stream>>>(feat1, feat2, out);
}

// Round 6
// 304.769 us; speedup vs baseline: 1.5657x; 1.5657x over previous
//
#include <hip/hip_runtime.h>

#define BB 8
#define CC_ALL 128
#define HH 160
#define WW 160
#define PAD 4
#define RANGE 9
#define ND 80
#define NG 3                  // di groups (rows 0-2, 3-5, 6-8)
#define DR 3                  // di rows per group -> one per thread
#define TH 8                  // tile height (full width tile: 160 x 8)
#define NTX 40                // lanes per image row
#define PXT 4                 // px per thread along w (aligned float4)
#define NTHREADS 960          // tx(40) * r(3) * ty(8) = 15 waves
#define CCHUNK 4              // double-buffered
#define NBUF 2
#define NROWS (TH + DR - 1)   // 10 f2 rows cover this group's 3 di offsets
#define ROWF (WW + 2 * PAD)   // 168 floats per LDS row (1 pad quad each side)
#define QROW (ROWF / 4)       // 42 float4 per row
#define NQUADS (CCHUNK * NROWS * QROW)   // 1680 float4 per chunk
#define BSTRIDE (1728 * 4)    // buffer stride in floats, padded to wave multiple
#define PLANE (HH * WW)       // 25600
#define NSLOT 2               // ceil(1680/960)
#define NACC (RANGE * PXT)    // 36 accumulators per thread
#define NCHUNK (CC_ALL / CCHUNK)   // 32

// zero-initialized device global: staged into LDS pad/OOB slots each chunk
__device__ __attribute__((aligned(16))) float g_zero[1024];

// async global->LDS, 16B per lane; dest = wave-uniform base + lane*16 (m104)
#define GLOAD_LDS16(gp, lp)                                                    \
    __builtin_amdgcn_global_load_lds(                                          \
        (const __attribute__((address_space(1))) unsigned int*)(gp),           \
        (__attribute__((address_space(3))) unsigned int*)(lp), 16, 0, 0)

// Second launch_bounds arg MUST stay 1 (rounds 1-3: spill). No register
// staging buffers of any kind (rounds 2/3/5: allocator spills them).
__global__ __launch_bounds__(NTHREADS, 1)
void cost_volume_kernel(const float* __restrict__ f1,
                        const float* __restrict__ f2,
                        float* __restrict__ out) {
    __shared__ __align__(16) float s2[NBUF * BSTRIDE];   // 55.3 KB

    const int tile_y = blockIdx.x;              // 0..19
    const int bz     = blockIdx.y;              // 0..23
    const int b = bz / NG;
    const int g = bz - b * NG;                  // di group
    const int h0 = tile_y * TH;
    const int tid = threadIdx.x;
    // lane order tx -> r -> ty: duplicate f1 addresses coalesce in-wave
    const int tx = tid % NTX;                   // 0..39
    const int r  = (tid / NTX) % DR;            // 0..2  (this thread's di row)
    const int ty = tid / (NTX * DR);            // 0..7
    const int w = tx * PXT;                     // multiple of 4
    const int h = h0 + ty;
    const int row_start = h0 + DR * g - PAD;    // image row of LDS row 0
    const int wv = __builtin_amdgcn_readfirstlane(tid >> 6);  // wave id (SGPR)

    const float* f2b = f2 + (size_t)b * CC_ALL * PLANE;

    // ---- per-lane staging descriptors ----
    // slot s -> (cc, row, quad); quad 0 and 41 are pad quads -> zero source.
    // LDS is slot-linear: slot s lives at s2[buf] + s*4 floats.
    const float* gsrc[NSLOT];
    int gstep[NSLOT];
    bool gval[NSLOT];
    int lbase[NSLOT];                           // wave-uniform slot base
#pragma unroll
    for (int k = 0; k < NSLOT; k++) {
        const int s = tid + k * NTHREADS;
        const int quad = s % QROW;
        const int t = s / QROW;
        const int row = t % NROWS;
        const int cc = t / NROWS;
        const int gh = row_start + row;
        const bool data = (quad >= 1) && (quad <= 40) && ((unsigned)gh < HH);
        gval[k]  = (s < NQUADS);
        gsrc[k]  = data ? (f2b + (size_t)cc * PLANE + (size_t)gh * WW + (quad - 1) * 4)
                        : (g_zero + ((s & 63) << 2));
        gstep[k] = data ? CCHUNK * PLANE : 0;   // zero-source lanes never advance
        lbase[k] = (wv * 64 + k * NTHREADS) * 4;   // float offset, wave-uniform
    }

    float acc[NACC];
#pragma unroll
    for (int i = 0; i < NACC; i++) acc[i] = 0.f;

    const float* f1p = f1 + (size_t)b * CC_ALL * PLANE + (size_t)h * WW + w;

    // ---- prologue: async-stage chunk 0 into buf 0 ----
#pragma unroll
    for (int k = 0; k < NSLOT; k++) {
        if (gval[k]) {
            GLOAD_LDS16(gsrc[k], s2 + lbase[k]);
            gsrc[k] += gstep[k];
        }
    }
    __syncthreads();   // vmcnt(0) drain: chunk 0 resident

    // ---- main loop: issue async stage of it+1, compute it, one barrier ----
    for (int it = 0; it < NCHUNK; ++it) {
        if (it + 1 < NCHUNK) {
            float* nb = s2 + ((it + 1) & 1) * BSTRIDE;
#pragma unroll
            for (int k = 0; k < NSLOT; k++) {
                if (gval[k]) {
                    GLOAD_LDS16(gsrc[k], nb + lbase[k]);
                    gsrc[k] += gstep[k];
                }
            }
        }

        const int c0 = it * CCHUNK;
        const float* bufp = s2 + (it & 1) * BSTRIDE;
#pragma unroll
        for (int cc = 0; cc < CCHUNK; cc++) {
            const float4 a = *(const float4*)(f1p + (size_t)(c0 + cc) * PLANE);
            const float av[PXT] = {a.x, a.y, a.z, a.w};
            // LDS array cols w .. w+11  <->  image cols w-4 .. w+7 (pads = 0)
            const float* rp = bufp + (cc * NROWS + ty + r) * ROWF + w;
            float win[12];
            *(float4*)&win[0] = *(const float4*)(rp);
            *(float4*)&win[4] = *(const float4*)(rp + 4);
            *(float4*)&win[8] = *(const float4*)(rp + 8);
#pragma unroll
            for (int dj = 0; dj < RANGE; dj++) {
#pragma unroll
                for (int p = 0; p < PXT; p++) {
                    acc[dj * PXT + p] += av[p] * win[dj + p];
                }
            }
        }
        __syncthreads();   // drains prefetch vmcnt + protects buffer swap
    }

    // ---- epilogue: mean and store (skip center lin==40) ----
    float* ob = out + (size_t)b * ND * PLANE + (size_t)h * WW + w;
#pragma unroll
    for (int dj = 0; dj < RANGE; dj++) {
        const int lin = (DR * g + r) * RANGE + dj;
        if (lin == 40) continue;                // center displacement excluded
        const int d = lin - (lin > 40 ? 1 : 0);
        float4 o;
        o.x = acc[dj * PXT + 0] * (1.f / 128.f);
        o.y = acc[dj * PXT + 1] * (1.f / 128.f);
        o.z = acc[dj * PXT + 2] * (1.f / 128.f);
        o.w = acc[dj * PXT + 3] * (1.f / 128.f);
        *(float4*)(ob + (size_t)d * PLANE) = o;
    }
}

extern "C" void kernel_launch(void* const* d_in, const int* in_sizes, int n_in,
                              void* d_out, int out_size, void* d_ws, size_t ws_size,
                              hipStream_t stream) {
    const float* feat1 = (const float*)d_in[0];
    const float* feat2 = (const float*)d_in[1];
    float* out = (float*)d_out;

    dim3 grid(HH / TH, BB * NG);   // 20 x 24 = 480 blocks of 15 waves
    dim3 block(NTHREADS);
    cost_volume_kernel<<<grid, block, 0, stream>>>(feat1, feat2, out);
}